// Round 8
// baseline (315.242 us; speedup 1.0000x reference)
//
#include <hip/hip_runtime.h>
#include <math.h>

// Problem constants (from reference)
constexpr int cS  = 16;   // sequence
constexpr int cB  = 8;    // batch
constexpr int cNC = 5;    // classes
constexpr int cD  = 256;  // hidden
constexpr int cP  = 16;   // patches
constexpr int cPD = 49;   // patch dim
#define LEPS 1e-5f
// per-group scan scratch stride (floats): x[16][16] + eq[16]+ek[16]+bsig[16]
// = 304, padded to 328 (328%32==8 -> 2-way-free bank pattern, 16B aligned)
#define GSTR 328

__device__ __forceinline__ float frcp(float x) { return __builtin_amdgcn_rcpf(x); }
__device__ __forceinline__ float sigm(float x) { return frcp(1.0f + __expf(-x)); }
__device__ __forceinline__ float gelu_t(float x) {
  const float z = 1.5957691216057308f * (x + 0.044715f * x * x * x);
  return x * frcp(1.0f + __expf(-z));
}

template<int CTRL>
__device__ __forceinline__ float dpp_mov(float v) {
  return __int_as_float(__builtin_amdgcn_update_dpp(
      0, __float_as_int(v), CTRL, 0xF, 0xF, true));
}
__device__ __forceinline__ float row_sum16(float v) {
  v += dpp_mov<0xB1>(v);   // quad_perm [1,0,3,2]
  v += dpp_mov<0x4E>(v);   // quad_perm [2,3,0,1]
  v += dpp_mov<0x124>(v);  // row_ror:4
  v += dpp_mov<0x128>(v);  // row_ror:8
  return v;
}
__device__ __forceinline__ float wave_sum64(float v) {
  v = row_sum16(v);
  v += __shfl_xor(v, 16, 64);
  v += __shfl_xor(v, 32, 64);
  return v;
}

// 16-dot with 4-way split chains (4-deep FMA chains + tree).
__device__ __forceinline__ float dot16(const float (&w)[16],
    const float4 a, const float4 b, const float4 c, const float4 d) {
  float s0 = w[0]  * a.x; s0 += w[1]  * a.y; s0 += w[2]  * a.z; s0 += w[3]  * a.w;
  float s1 = w[4]  * b.x; s1 += w[5]  * b.y; s1 += w[6]  * b.z; s1 += w[7]  * b.w;
  float s2 = w[8]  * c.x; s2 += w[9]  * c.y; s2 += w[10] * c.z; s2 += w[11] * c.w;
  float s3 = w[12] * d.x; s3 += w[13] * d.y; s3 += w[14] * d.z; s3 += w[15] * d.w;
  return (s0 + s1) + (s2 + s3);
}

// ---- scan prologue: pre-broadcast all 16 x-vectors into group scratch ----
__device__ __forceinline__ void srwm_prestage(
    const float (&xp)[16], float* gl, const int r) {
#pragma unroll
  for (int s = 0; s < 16; ++s) gl[s * 16 + r] = xp[s];
  __builtin_amdgcn_wave_barrier();
}

// ---- SRWM step, pre-staged x: only ONE LDS round-trip (eq/ek/bsig) on the
// ---- per-step critical path. Wave-internal DS ordering is in-order.
__device__ __forceinline__ float srwm_step(
    float (&wy)[16], float (&wq)[16], float (&wk)[16], float (&wbr)[16],
    float* gl, const int r, const int s) {
  const float4* xg = (const float4*)(gl + s * 16);
  const float4 xa = xg[0], xb = xg[1], xc = xg[2], xd = xg[3];
  const float y  = dot16(wy,  xa, xb, xc, xd);
  const float q  = dot16(wq,  xa, xb, xc, xd);
  const float k  = dot16(wk,  xa, xb, xc, xd);
  const float bt = dot16(wbr, xa, xb, xc, xd);
  const float bsig = sigm(bt);
  const float eq = __expf(q), ek = __expf(k);
  gl[256 + r] = eq;
  gl[272 + r] = ek;
  gl[288 + r] = bsig;
  __builtin_amdgcn_wave_barrier();
  const float4* g4 = (const float4*)(gl + 256);
  const float4 qa = g4[0], qb = g4[1], qc = g4[2], qd = g4[3];
  const float4 ka = g4[4], kb = g4[5], kc = g4[6], kd = g4[7];
  const float4 bs4 = g4[8];
  const float ay  = dot16(wy,  qa, qb, qc, qd);
  const float vqq = dot16(wq,  qa, qb, qc, qd);
  const float vkq = dot16(wk,  qa, qb, qc, qd);
  const float vbq = dot16(wbr, qa, qb, qc, qd);
  const float vyk = dot16(wy,  ka, kb, kc, kd);
  const float vqk = dot16(wq,  ka, kb, kc, kd);
  const float vkk = dot16(wk,  ka, kb, kc, kd);
  const float vbk = dot16(wbr, ka, kb, kc, kd);
  const float sq = ((qa.x + qa.y) + (qa.z + qa.w)) + ((qb.x + qb.y) + (qb.z + qb.w))
                 + ((qc.x + qc.y) + (qc.z + qc.w)) + ((qd.x + qd.y) + (qd.z + qd.w));
  const float sk = ((ka.x + ka.y) + (ka.z + ka.w)) + ((kb.x + kb.y) + (kb.z + kb.w))
                 + ((kc.x + kc.y) + (kc.z + kc.w)) + ((kd.x + kd.y) + (kd.z + kd.w));
  const float rq = frcp(sq);
  const float rk = frcp(sk);
  const float ea = __expf(ay * rq);
  const float vyq = ea * frcp(row_sum16(ea));
  const float cy = bs4.x * (vyq      - vyk * rk) * rk;
  const float cq = bs4.y * (vqq * rq - vqk * rk) * rk;
  const float ck = bs4.z * (vkq * rq - vkk * rk) * rk;
  const float cb = bs4.w * (vbq * rq - vbk * rk) * rk;
  const float ks[16] = {ka.x, ka.y, ka.z, ka.w, kb.x, kb.y, kb.z, kb.w,
                        kc.x, kc.y, kc.z, kc.w, kd.x, kd.y, kd.z, kd.w};
#pragma unroll
  for (int j = 0; j < 16; ++j) {
    wy[j] += cy * ks[j]; wq[j] += cq * ks[j]; wk[j] += ck * ks[j]; wbr[j] += cb * ks[j];
  }
  return y;
}

// ---------------- embed: patchify + one-hot concat + linear ----------------
__global__ __launch_bounds__(256) void k_embed(const float* __restrict__ x,
                                               const int* __restrict__ fb,
                                               const float* __restrict__ inW,
                                               const float* __restrict__ inb,
                                               float* __restrict__ h) {
  const int blk = blockIdx.x;
  const int p  = blk & 15;
  const int sb = blk >> 4;
  const int ph = p >> 2, pw = p & 3;
  __shared__ float sx[cPD];
  const int t = threadIdx.x;
  if (t < cPD) {
    const int p1 = t / 7, p2 = t % 7;
    sx[t] = x[(size_t)sb * 784 + (ph * 7 + p1) * 28 + (pw * 7 + p2)];
  }
  __syncthreads();
  const int cls = fb[sb];
  float acc = inb[t] + inW[(size_t)(cPD + cls) * cD + t];
#pragma unroll
  for (int j = 0; j < cPD; ++j) acc += sx[j] * inW[(size_t)j * cD + t];
  h[((size_t)sb * cP + p) * cD + t] = acc;
}

// --------- token SRWM: 256 blocks x 128 threads (all 256 CUs) --------------
__global__ __launch_bounds__(128) void k_tok_srwm(
    float* __restrict__ h, const float* __restrict__ Wy0, const float* __restrict__ Wq0,
    const float* __restrict__ Wk0, const float* __restrict__ wb0,
    const float* __restrict__ lng, const float* __restrict__ lnb) {
  const int t    = threadIdx.x;
  const int lane = t & 63;
  const int w    = t >> 6;              // 0..1
  const int r    = lane & 15;
  const int li   = lane >> 4;
  const int b    = blockIdx.x >> 5;     // 8 b x 32 dgroups
  const int d    = ((blockIdx.x & 31) << 3) + (w << 2) + li;
  __shared__ __align__(16) float gscr[8][GSTR];
  float* gl = gscr[t >> 4];
  float wy[16], wq[16], wk[16], wbr[16];
#pragma unroll
  for (int j = 0; j < 16; ++j) {
    wy[j]  = Wy0[r * 16 + j];
    wq[j]  = Wq0[r * 16 + j];
    wk[j]  = Wk0[r * 16 + j];
    wbr[j] = wb0[(r & 3) * 16 + j];
  }
  const float gg = lng[r], bb = lnb[r];
  float xp[16];
#pragma unroll
  for (int s = 0; s < 16; ++s)
    xp[s] = h[((size_t)(s * cB + b) * cP + r) * cD + d];
  srwm_prestage(xp, gl, r);
  for (int s = 0; s < cS; ++s) {
    const float y = srwm_step(wy, wq, wk, wbr, gl, r, s);
    const float s1 = row_sum16(y);
    const float s2 = row_sum16(y * y);
    const float m = s1 * 0.0625f;
    const float var = s2 * 0.0625f - m * m;
    h[((size_t)(s * cB + b) * cP + r) * cD + d] = (y - m) * rsqrtf(var + LEPS) * gg + bb;
  }
}

// ---------------- token mixer: LN(D) then FFN over patch axis --------------
__global__ __launch_bounds__(256) void k_tok_mixer(
    float* __restrict__ h, const float* __restrict__ g, const float* __restrict__ bta,
    const float* __restrict__ W1, const float* __restrict__ b1,
    const float* __restrict__ W2, const float* __restrict__ b2) {
  const int sb = blockIdx.x;
  const int t = threadIdx.x;
  __shared__ float tile[16][256];
  __shared__ float W1s[16 * 64], W2s[64 * 16];
  __shared__ float mean_[16], rstd_[16];
  __shared__ float red[16][17], red2[16][17];
  const size_t base = (size_t)sb * cP * cD;
#pragma unroll
  for (int p = 0; p < 16; ++p) tile[p][t] = h[base + p * 256 + t];
  W1s[t] = W1[t]; W1s[t + 256] = W1[t + 256]; W1s[t + 512] = W1[t + 512]; W1s[t + 768] = W1[t + 768];
  W2s[t] = W2[t]; W2s[t + 256] = W2[t + 256]; W2s[t + 512] = W2[t + 512]; W2s[t + 768] = W2[t + 768];
  __syncthreads();
  const int p = t >> 4, l = t & 15;
  float ps = 0.f, ps2 = 0.f;
#pragma unroll
  for (int k = 0; k < 16; ++k) { const float v = tile[p][l + 16 * k]; ps += v; ps2 += v * v; }
  red[p][l] = ps; red2[p][l] = ps2;
  __syncthreads();
  if (t < 16) {
    float sm = 0.f, s2 = 0.f;
#pragma unroll
    for (int k = 0; k < 16; ++k) { sm += red[t][k]; s2 += red2[t][k]; }
    const float m = sm * (1.f / 256.f);
    mean_[t] = m;
    rstd_[t] = rsqrtf(s2 * (1.f / 256.f) - m * m + LEPS);
  }
  __syncthreads();
  const float gd = g[t], bd = bta[t];
  float v[16], out[16];
#pragma unroll
  for (int pp = 0; pp < 16; ++pp) {
    v[pp] = (tile[pp][t] - mean_[pp]) * rstd_[pp] * gd + bd;
    out[pp] = b2[pp];
  }
  for (int e = 0; e < 64; ++e) {
    float acc = b1[e];
#pragma unroll
    for (int pp = 0; pp < 16; ++pp) acc += v[pp] * W1s[pp * 64 + e];
    const float ge = gelu_t(acc);
#pragma unroll
    for (int pp = 0; pp < 16; ++pp) out[pp] += ge * W2s[e * 16 + pp];
  }
#pragma unroll
  for (int pp = 0; pp < 16; ++pp) h[base + pp * 256 + t] = tile[pp][t] + out[pp];
}

// --------- channel SRWM scan: 256 blocks x 128 threads (8 heads each) ------
__global__ __launch_bounds__(128) void k_ch_scan(
    const float* __restrict__ h, float* __restrict__ y2,
    const float* __restrict__ Wy0, const float* __restrict__ Wq0,
    const float* __restrict__ Wk0, const float* __restrict__ wb0) {
  const int t  = threadIdx.x;
  const int hg = blockIdx.x & 1;        // head group (0: heads 0-7, 1: 8-15)
  const int bp = blockIdx.x >> 1;       // (b,p) instance
  const int hh = (hg << 3) + (t >> 4);  // global head
  const int r  = t & 15;
  const int d  = (hg << 7) + t;         // = hh*16 + r
  __shared__ __align__(16) float gscr[8][GSTR];
  float* gl = gscr[t >> 4];
  float wy[16], wq[16], wk[16], wbr[16];
#pragma unroll
  for (int j = 0; j < 16; ++j) {
    wy[j]  = Wy0[(hh * 16 + r) * 16 + j];
    wq[j]  = Wq0[(hh * 16 + r) * 16 + j];
    wk[j]  = Wk0[(hh * 16 + r) * 16 + j];
    wbr[j] = wb0[(hh * 4 + (r & 3)) * 16 + j];
  }
  float xp[16];
#pragma unroll
  for (int s = 0; s < 16; ++s)
    xp[s] = h[(size_t)(s * cB * cP + bp) * cD + d];
  srwm_prestage(xp, gl, r);
  for (int s = 0; s < cS; ++s)
    y2[(size_t)(s * cB * cP + bp) * cD + d] = srwm_step(wy, wq, wk, wbr, gl, r, s);
}

// --------- channel LN1 + mixer: 256 blocks x 512 threads, 8 rows each ------
// R8: weights staged through LDS in double-buffered 32 KB chunks. Previously
// each of the 8 row-groups streamed full W1+W2 through L1 (2 MB/CU, ~14 us at
// 64 B/clk); now global traffic is 256 KB/block and the redundant reads hit
// LDS at 256 B/clk (~3.5 us).
__global__ __launch_bounds__(512) void k_ch_ln_mix(
    const float* __restrict__ y2, float* __restrict__ h,
    const float* __restrict__ lng, const float* __restrict__ lnb,
    const float* __restrict__ mg, const float* __restrict__ mb,
    const float* __restrict__ W1, const float* __restrict__ b1,
    const float* __restrict__ W2, const float* __restrict__ b2) {
  const int u = threadIdx.x;
  const int t = u & 255;
  const int jh = u >> 8;                // 0/1: row-half within each chunk
  const int row0 = blockIdx.x * 8;
  __shared__ float yv[8][256];          // rows; reused as W2-partial buffer
  __shared__ float lnv[8][256];
  __shared__ float hid[8][128];
  __shared__ float part1[8][128];
  __shared__ __align__(16) float wbuf[2][8192];   // 2 x 32 KB weight chunks
  // cooperative load of 8 consecutive rows (2048 consecutive floats)
  const float4* yp4 = (const float4*)(y2 + (size_t)row0 * cD);
  ((float4*)yv)[u] = yp4[u];
  // stage W1 chunk 0 (rows 0..63 of 256) while LN phase runs
  {
    const float4* src = (const float4*)W1;
#pragma unroll
    for (int kk = 0; kk < 4; ++kk)
      ((float4*)wbuf[0])[u + kk * 512] = src[u + kk * 512];
  }
  __syncthreads();
  const int r32 = t >> 5, l = t & 31;
  float4 a0, a1;   // SRWM-LN output (mixer residual input), jh==0 only
  if (jh == 0) {
    const float4 eg0 = ((const float4*)lng)[l * 2];
    const float4 eg1 = ((const float4*)lng)[l * 2 + 1];
    const float4 eb0 = ((const float4*)lnb)[l * 2];
    const float4 eb1 = ((const float4*)lnb)[l * 2 + 1];
    const float4 mg0 = ((const float4*)mg)[l * 2];
    const float4 mg1 = ((const float4*)mg)[l * 2 + 1];
    const float4 mb0 = ((const float4*)mb)[l * 2];
    const float4 mb1 = ((const float4*)mb)[l * 2 + 1];
    const float4 y0 = ((const float4*)yv[r32])[l * 2];
    const float4 y1 = ((const float4*)yv[r32])[l * 2 + 1];
    float s1 = y0.x + y0.y + y0.z + y0.w + y1.x + y1.y + y1.z + y1.w;
    float s2 = y0.x * y0.x + y0.y * y0.y + y0.z * y0.z + y0.w * y0.w +
               y1.x * y1.x + y1.y * y1.y + y1.z * y1.z + y1.w * y1.w;
#pragma unroll
    for (int o = 1; o < 32; o <<= 1) {
      s1 += __shfl_xor(s1, o, 32);
      s2 += __shfl_xor(s2, o, 32);
    }
    const float m1 = s1 * (1.f / 256.f);
    const float rst1 = rsqrtf(s2 * (1.f / 256.f) - m1 * m1 + LEPS);
    a0.x = (y0.x - m1) * rst1 * eg0.x + eb0.x; a0.y = (y0.y - m1) * rst1 * eg0.y + eb0.y;
    a0.z = (y0.z - m1) * rst1 * eg0.z + eb0.z; a0.w = (y0.w - m1) * rst1 * eg0.w + eb0.w;
    a1.x = (y1.x - m1) * rst1 * eg1.x + eb1.x; a1.y = (y1.y - m1) * rst1 * eg1.y + eb1.y;
    a1.z = (y1.z - m1) * rst1 * eg1.z + eb1.z; a1.w = (y1.w - m1) * rst1 * eg1.w + eb1.w;
    float u1 = a0.x + a0.y + a0.z + a0.w + a1.x + a1.y + a1.z + a1.w;
    float u2 = a0.x * a0.x + a0.y * a0.y + a0.z * a0.z + a0.w * a0.w +
               a1.x * a1.x + a1.y * a1.y + a1.z * a1.z + a1.w * a1.w;
#pragma unroll
    for (int o = 1; o < 32; o <<= 1) {
      u1 += __shfl_xor(u1, o, 32);
      u2 += __shfl_xor(u2, o, 32);
    }
    const float m2 = u1 * (1.f / 256.f);
    const float rst2 = rsqrtf(u2 * (1.f / 256.f) - m2 * m2 + LEPS);
    float4 L0, L1;
    L0.x = (a0.x - m2) * rst2 * mg0.x + mb0.x; L0.y = (a0.y - m2) * rst2 * mg0.y + mb0.y;
    L0.z = (a0.z - m2) * rst2 * mg0.z + mb0.z; L0.w = (a0.w - m2) * rst2 * mg0.w + mb0.w;
    L1.x = (a1.x - m2) * rst2 * mg1.x + mb1.x; L1.y = (a1.y - m2) * rst2 * mg1.y + mb1.y;
    L1.z = (a1.z - m2) * rst2 * mg1.z + mb1.z; L1.w = (a1.w - m2) * rst2 * mg1.w + mb1.w;
    ((float4*)lnv[r32])[l * 2]     = L0;
    ((float4*)lnv[r32])[l * 2 + 1] = L1;
  }
  __syncthreads();
  // ---- W1 GEMV: hid = gelu(lnv @ W1 + b1); 4 chunks of 64 k-rows, jh
  // ---- halves each chunk (rows jh*32..jh*32+31) -> chains stay split.
  {
    float4 acc;
    if (jh == 0) acc = ((const float4*)b1)[l];
    else         acc = make_float4(0.f, 0.f, 0.f, 0.f);
    const float* xrow = lnv[r32];
    for (int c = 0; c < 4; ++c) {
      float4 pf[4];
      if (c < 3) {
        const float4* src = (const float4*)W1 + (c + 1) * 2048;
#pragma unroll
        for (int kk = 0; kk < 4; ++kk) pf[kk] = src[u + kk * 512];
      }
      const float* wc = wbuf[c & 1];          // [64 rows][128 cols]
      const float4* wc4 = (const float4*)wc;
      const int jbase = c * 64 + jh * 32;     // global k-row base
#pragma unroll
      for (int j4 = 0; j4 < 8; ++j4) {
        const int jr = jh * 32 + j4 * 4;      // row within chunk
        const float4 xv = *(const float4*)(xrow + jbase + j4 * 4);
        const float4 w0 = wc4[(jr + 0) * 32 + l];
        const float4 w1 = wc4[(jr + 1) * 32 + l];
        const float4 w2 = wc4[(jr + 2) * 32 + l];
        const float4 w3 = wc4[(jr + 3) * 32 + l];
        acc.x += xv.x * w0.x + xv.y * w1.x + xv.z * w2.x + xv.w * w3.x;
        acc.y += xv.x * w0.y + xv.y * w1.y + xv.z * w2.y + xv.w * w3.y;
        acc.z += xv.x * w0.z + xv.y * w1.z + xv.z * w2.z + xv.w * w3.z;
        acc.w += xv.x * w0.w + xv.y * w1.w + xv.z * w2.w + xv.w * w3.w;
      }
      if (c < 3) {
        __syncthreads();                      // chunk c readers done
        float4* dst = (float4*)wbuf[(c + 1) & 1];
#pragma unroll
        for (int kk = 0; kk < 4; ++kk) dst[u + kk * 512] = pf[kk];
        __syncthreads();                      // chunk c+1 visible
      }
    }
    if (jh == 1) ((float4*)part1[r32])[l] = acc;
    __syncthreads();
    if (jh == 0) {
      const float4 p = ((const float4*)part1[r32])[l];
      float4 hv;
      hv.x = gelu_t(acc.x + p.x); hv.y = gelu_t(acc.y + p.y);
      hv.z = gelu_t(acc.z + p.z); hv.w = gelu_t(acc.w + p.w);
      ((float4*)hid[r32])[l] = hv;
    }
    __syncthreads();
  }
  // ---- W2 GEMV: out = hid @ W2 + b2 (+residual); 4 chunks of 32 e-rows ----
  {
    float4 o0, o1;
    if (jh == 0) { o0 = ((const float4*)b2)[l * 2]; o1 = ((const float4*)b2)[l * 2 + 1]; }
    else         { o0 = make_float4(0.f, 0.f, 0.f, 0.f); o1 = o0; }
    // stage W2 chunk 0
    {
      const float4* src = (const float4*)W2;
#pragma unroll
      for (int kk = 0; kk < 4; ++kk) ((float4*)wbuf[0])[u + kk * 512] = src[u + kk * 512];
    }
    __syncthreads();
    const float* hrow = hid[r32];
    for (int c = 0; c < 4; ++c) {
      float4 pf[4];
      if (c < 3) {
        const float4* src = (const float4*)W2 + (c + 1) * 2048;
#pragma unroll
        for (int kk = 0; kk < 4; ++kk) pf[kk] = src[u + kk * 512];
      }
      const float4* wc4 = (const float4*)wbuf[c & 1];   // [32 rows][256 cols]
      const int ebase = c * 32 + jh * 16;               // global e base
#pragma unroll
      for (int ee = 0; ee < 16; ++ee) {
        const int er = jh * 16 + ee;                    // row within chunk
        const float xv = hrow[ebase + ee];
        const float4 w0 = wc4[er * 64 + l * 2];
        const float4 w1 = wc4[er * 64 + l * 2 + 1];
        o0.x += xv * w0.x; o0.y += xv * w0.y; o0.z += xv * w0.z; o0.w += xv * w0.w;
        o1.x += xv * w1.x; o1.y += xv * w1.y; o1.z += xv * w1.z; o1.w += xv * w1.w;
      }
      if (c < 3) {
        __syncthreads();
        float4* dst = (float4*)wbuf[(c + 1) & 1];
#pragma unroll
        for (int kk = 0; kk < 4; ++kk) dst[u + kk * 512] = pf[kk];
        __syncthreads();
      }
    }
    if (jh == 1) {
      ((float4*)yv[r32])[l * 2]     = o0;   // yv dead: reuse as partial buf
      ((float4*)yv[r32])[l * 2 + 1] = o1;
    }
    __syncthreads();
    if (jh == 0) {
      const float4 p0 = ((const float4*)yv[r32])[l * 2];
      const float4 p1 = ((const float4*)yv[r32])[l * 2 + 1];
      o0.x += p0.x + a0.x; o0.y += p0.y + a0.y; o0.z += p0.z + a0.z; o0.w += p0.w + a0.w;
      o1.x += p1.x + a1.x; o1.y += p1.y + a1.y; o1.z += p1.z + a1.z; o1.w += p1.w + a1.w;
      float4* op = (float4*)(h + ((size_t)row0 + r32) * cD);
      op[l * 2]     = o0;
      op[l * 2 + 1] = o1;
    }
  }
}

// ---------------- final LN + mean over patches -----------------------------
__global__ __launch_bounds__(256) void k_fln_mean(
    const float* __restrict__ h, const float* __restrict__ gg, const float* __restrict__ bbv,
    float* __restrict__ o) {
  const int sb = blockIdx.x;
  const int t = threadIdx.x;
  const int lane = t & 63, w = t >> 6;
  const float4 g4 = ((const float4*)gg)[lane];
  const float4 b4 = ((const float4*)bbv)[lane];
  float a0 = 0.f, a1 = 0.f, a2 = 0.f, a3 = 0.f;
  for (int pp = 0; pp < 4; ++pp) {
    const int p = w * 4 + pp;
    const float4 v4 = ((const float4*)(h + ((size_t)sb * cP + p) * cD))[lane];
    const float s1 = wave_sum64(v4.x + v4.y + v4.z + v4.w);
    const float s2 = wave_sum64(v4.x * v4.x + v4.y * v4.y + v4.z * v4.z + v4.w * v4.w);
    const float m = s1 * (1.f / 256.f);
    const float rst = rsqrtf(s2 * (1.f / 256.f) - m * m + LEPS);
    a0 += (v4.x - m) * rst * g4.x + b4.x;
    a1 += (v4.y - m) * rst * g4.y + b4.y;
    a2 += (v4.z - m) * rst * g4.z + b4.z;
    a3 += (v4.w - m) * rst * g4.w + b4.w;
  }
  __shared__ float sacc[4][256];
  float4* sp = (float4*)sacc[w];
  sp[lane] = make_float4(a0, a1, a2, a3);
  __syncthreads();
  o[(size_t)sb * cD + t] = (sacc[0][t] + sacc[1][t] + sacc[2][t] + sacc[3][t]) * (1.f / 16.f);
}

// -------- output SRWM: barrier-free scan + batched LN/projection ----------
__global__ __launch_bounds__(256, 1) void k_out_srwm(
    const float* __restrict__ gin, float* __restrict__ outp,
    const float* __restrict__ Wy0, const float* __restrict__ Wq0,
    const float* __restrict__ Wk0, const float* __restrict__ wb0,
    const float* __restrict__ lng, const float* __restrict__ lnb,
    const float* __restrict__ outW, const float* __restrict__ outb) {
  const int t = threadIdx.x;
  const int lane = t & 63;
  const int w = t >> 6;
  const int hh = t >> 4, r = t & 15;
  const int b = blockIdx.x;
  __shared__ float ymat[16][256];
  __shared__ float gwm[cNC][256];
  __shared__ float GBp[4][10];
  __shared__ float GBs[10];
  __shared__ __align__(16) float gscr[16][GSTR];
  float* gl = gscr[hh];
  float wy[16], wq[16], wk[16], wbr[16];
#pragma unroll
  for (int j = 0; j < 16; ++j) {
    wy[j]  = Wy0[(hh * 16 + r) * 16 + j];
    wq[j]  = Wq0[(hh * 16 + r) * 16 + j];
    wk[j]  = Wk0[(hh * 16 + r) * 16 + j];
    wbr[j] = wb0[(hh * 4 + (r & 3)) * 16 + j];
  }
  {
    const float gg = lng[t], bbl = lnb[t];
    float pg[cNC], pbv[cNC];
#pragma unroll
    for (int c = 0; c < cNC; ++c) {
      const float wv = outW[(size_t)t * cNC + c];
      const float gwv = gg * wv;
      gwm[c][t] = gwv;
      pg[c] = wave_sum64(gwv);
      pbv[c] = wave_sum64(bbl * wv);
    }
    if (lane == 0) {
#pragma unroll
      for (int c = 0; c < cNC; ++c) { GBp[w][c] = pg[c]; GBp[w][5 + c] = pbv[c]; }
    }
    __syncthreads();
    if (t < 10) GBs[t] = GBp[0][t] + GBp[1][t] + GBp[2][t] + GBp[3][t];
    __syncthreads();
  }
  float xp[16];
#pragma unroll
  for (int s = 0; s < 16; ++s) xp[s] = gin[(size_t)(s * cB + b) * cD + t];
  srwm_prestage(xp, gl, r);
  for (int s = 0; s < cS; ++s)
    ymat[s][t] = srwm_step(wy, wq, wk, wbr, gl, r, s);
  __syncthreads();
  for (int k2 = 0; k2 < 4; ++k2) {
    const int sidx = w * 4 + k2;
    const float4 y4 = ((const float4*)ymat[sidx])[lane];
    const float s1 = wave_sum64(y4.x + y4.y + y4.z + y4.w);
    const float s2 = wave_sum64(y4.x * y4.x + y4.y * y4.y + y4.z * y4.z + y4.w * y4.w);
    float S[cNC];
#pragma unroll
    for (int c = 0; c < cNC; ++c) {
      const float4 g4 = ((const float4*)gwm[c])[lane];
      S[c] = wave_sum64(y4.x * g4.x + y4.y * g4.y + y4.z * g4.z + y4.w * g4.w);
    }
    if (lane == 0) {
      const float m = s1 * (1.f / 256.f);
      const float var = s2 * (1.f / 256.f) - m * m;
      const float rst = rsqrtf(var + LEPS);
#pragma unroll
      for (int c = 0; c < cNC; ++c) {
        outp[(size_t)(sidx * cB + b) * cNC + c] =
            outb[c] + rst * S[c] - rst * m * GBs[c] + GBs[5 + c];
      }
    }
  }
}

extern "C" void kernel_launch(void* const* d_in, const int* in_sizes, int n_in,
                              void* d_out, int out_size, void* d_ws, size_t ws_size,
                              hipStream_t stream) {
  const float* x     = (const float*)d_in[0];
  const int*   fb    = (const int*)d_in[1];
  const float* inW   = (const float*)d_in[2];
  const float* inb   = (const float*)d_in[3];
  const float* tkWy  = (const float*)d_in[4];
  const float* tkWq  = (const float*)d_in[5];
  const float* tkWk  = (const float*)d_in[6];
  const float* tkwb  = (const float*)d_in[7];
  const float* tklng = (const float*)d_in[8];
  const float* tklnb = (const float*)d_in[9];
  const float* tkmg  = (const float*)d_in[10];
  const float* tkmb  = (const float*)d_in[11];
  const float* tkmW1 = (const float*)d_in[12];
  const float* tkmb1 = (const float*)d_in[13];
  const float* tkmW2 = (const float*)d_in[14];
  const float* tkmb2 = (const float*)d_in[15];
  const float* chWy  = (const float*)d_in[16];
  const float* chWq  = (const float*)d_in[17];
  const float* chWk  = (const float*)d_in[18];
  const float* chwb  = (const float*)d_in[19];
  const float* chlng = (const float*)d_in[20];
  const float* chlnb = (const float*)d_in[21];
  const float* chmg  = (const float*)d_in[22];
  const float* chmb  = (const float*)d_in[23];
  const float* chmW1 = (const float*)d_in[24];
  const float* chmb1 = (const float*)d_in[25];
  const float* chmW2 = (const float*)d_in[26];
  const float* chmb2 = (const float*)d_in[27];
  const float* flng  = (const float*)d_in[28];
  const float* flnb  = (const float*)d_in[29];
  const float* oWy   = (const float*)d_in[30];
  const float* oWq   = (const float*)d_in[31];
  const float* oWk   = (const float*)d_in[32];
  const float* owb   = (const float*)d_in[33];
  const float* olng  = (const float*)d_in[34];
  const float* olnb  = (const float*)d_in[35];
  const float* outW  = (const float*)d_in[36];
  const float* outb  = (const float*)d_in[37];

  float* h    = (float*)d_ws;                               // (S,B,P,D) 2 MB
  float* gbuf = h + (size_t)cS * cB * cP * cD;              // (S,B,D)
  float* y2   = gbuf + (size_t)cS * cB * cD;                // (S,B,P,D) 2 MB scratch
  float* outp = (float*)d_out;                              // (S,B,NC)

  k_embed<<<dim3(cS * cB * cP), dim3(256), 0, stream>>>(x, fb, inW, inb, h);
  for (int i = 0; i < 2; ++i) {
    k_tok_srwm<<<dim3(256), dim3(128), 0, stream>>>(
        h, tkWy + i * 256, tkWq + i * 256, tkWk + i * 256, tkwb + i * 64,
        tklng + i * 16, tklnb + i * 16);
    k_tok_mixer<<<dim3(cS * cB), dim3(256), 0, stream>>>(
        h, tkmg + i * 256, tkmb + i * 256, tkmW1 + i * 1024, tkmb1 + i * 64,
        tkmW2 + i * 1024, tkmb2 + i * 16);
    k_ch_scan<<<dim3(cB * cP * 2), dim3(128), 0, stream>>>(
        h, y2, chWy + i * 4096, chWq + i * 4096, chWk + i * 4096, chwb + i * 1024);
    k_ch_ln_mix<<<dim3(cS * cB * cP / 8), dim3(512), 0, stream>>>(
        y2, h, chlng + i * 256, chlnb + i * 256,
        chmg + i * 256, chmb + i * 256, chmW1 + i * 32768, chmb1 + i * 128,
        chmW2 + i * 32768, chmb2 + i * 256);
  }
  k_fln_mean<<<dim3(cS * cB), dim3(256), 0, stream>>>(h, flng, flnb, gbuf);
  k_out_srwm<<<dim3(cB), dim3(256), 0, stream>>>(
      gbuf, outp, oWy, oWq, oWk, owb, olng, olnb, outW, outb);
}

// Round 9
// 303.691 us; speedup vs baseline: 1.0380x; 1.0380x over previous
//
#include <hip/hip_runtime.h>
#include <math.h>

// Problem constants (from reference)
constexpr int cS  = 16;   // sequence
constexpr int cB  = 8;    // batch
constexpr int cNC = 5;    // classes
constexpr int cD  = 256;  // hidden
constexpr int cP  = 16;   // patches
constexpr int cPD = 49;   // patch dim
#define LEPS 1e-5f
// per-group scan scratch stride (floats): x[16][16] + eq[16]+ek[16]+bsig[16]
// = 304, padded to 328 (328%32==8 -> 2-way-free bank pattern, 16B aligned)
#define GSTR 328

__device__ __forceinline__ float frcp(float x) { return __builtin_amdgcn_rcpf(x); }
__device__ __forceinline__ float sigm(float x) { return frcp(1.0f + __expf(-x)); }
__device__ __forceinline__ float gelu_t(float x) {
  const float z = 1.5957691216057308f * (x + 0.044715f * x * x * x);
  return x * frcp(1.0f + __expf(-z));
}

template<int CTRL>
__device__ __forceinline__ float dpp_mov(float v) {
  return __int_as_float(__builtin_amdgcn_update_dpp(
      0, __float_as_int(v), CTRL, 0xF, 0xF, true));
}
__device__ __forceinline__ float row_sum16(float v) {
  v += dpp_mov<0xB1>(v);   // quad_perm [1,0,3,2]
  v += dpp_mov<0x4E>(v);   // quad_perm [2,3,0,1]
  v += dpp_mov<0x124>(v);  // row_ror:4
  v += dpp_mov<0x128>(v);  // row_ror:8
  return v;
}
__device__ __forceinline__ float wave_sum64(float v) {
  v = row_sum16(v);
  v += __shfl_xor(v, 16, 64);
  v += __shfl_xor(v, 32, 64);
  return v;
}

// 16-dot with 4-way split chains (4-deep FMA chains + tree).
__device__ __forceinline__ float dot16(const float (&w)[16],
    const float4 a, const float4 b, const float4 c, const float4 d) {
  float s0 = w[0]  * a.x; s0 += w[1]  * a.y; s0 += w[2]  * a.z; s0 += w[3]  * a.w;
  float s1 = w[4]  * b.x; s1 += w[5]  * b.y; s1 += w[6]  * b.z; s1 += w[7]  * b.w;
  float s2 = w[8]  * c.x; s2 += w[9]  * c.y; s2 += w[10] * c.z; s2 += w[11] * c.w;
  float s3 = w[12] * d.x; s3 += w[13] * d.y; s3 += w[14] * d.z; s3 += w[15] * d.w;
  return (s0 + s1) + (s2 + s3);
}

// ---- scan prologue: pre-broadcast all 16 x-vectors into group scratch ----
__device__ __forceinline__ void srwm_prestage(
    const float (&xp)[16], float* gl, const int r) {
#pragma unroll
  for (int s = 0; s < 16; ++s) gl[s * 16 + r] = xp[s];
  __builtin_amdgcn_wave_barrier();
}

// ---- SRWM step, pre-staged x: only ONE LDS round-trip (eq/ek/bsig) on the
// ---- per-step critical path. Wave-internal DS ordering is in-order.
__device__ __forceinline__ float srwm_step(
    float (&wy)[16], float (&wq)[16], float (&wk)[16], float (&wbr)[16],
    float* gl, const int r, const int s) {
  const float4* xg = (const float4*)(gl + s * 16);
  const float4 xa = xg[0], xb = xg[1], xc = xg[2], xd = xg[3];
  const float y  = dot16(wy,  xa, xb, xc, xd);
  const float q  = dot16(wq,  xa, xb, xc, xd);
  const float k  = dot16(wk,  xa, xb, xc, xd);
  const float bt = dot16(wbr, xa, xb, xc, xd);
  const float bsig = sigm(bt);
  const float eq = __expf(q), ek = __expf(k);
  gl[256 + r] = eq;
  gl[272 + r] = ek;
  gl[288 + r] = bsig;
  __builtin_amdgcn_wave_barrier();
  const float4* g4 = (const float4*)(gl + 256);
  const float4 qa = g4[0], qb = g4[1], qc = g4[2], qd = g4[3];
  const float4 ka = g4[4], kb = g4[5], kc = g4[6], kd = g4[7];
  const float4 bs4 = g4[8];
  const float ay  = dot16(wy,  qa, qb, qc, qd);
  const float vqq = dot16(wq,  qa, qb, qc, qd);
  const float vkq = dot16(wk,  qa, qb, qc, qd);
  const float vbq = dot16(wbr, qa, qb, qc, qd);
  const float vyk = dot16(wy,  ka, kb, kc, kd);
  const float vqk = dot16(wq,  ka, kb, kc, kd);
  const float vkk = dot16(wk,  ka, kb, kc, kd);
  const float vbk = dot16(wbr, ka, kb, kc, kd);
  const float sq = ((qa.x + qa.y) + (qa.z + qa.w)) + ((qb.x + qb.y) + (qb.z + qb.w))
                 + ((qc.x + qc.y) + (qc.z + qc.w)) + ((qd.x + qd.y) + (qd.z + qd.w));
  const float sk = ((ka.x + ka.y) + (ka.z + ka.w)) + ((kb.x + kb.y) + (kb.z + kb.w))
                 + ((kc.x + kc.y) + (kc.z + kc.w)) + ((kd.x + kd.y) + (kd.z + kd.w));
  const float rq = frcp(sq);
  const float rk = frcp(sk);
  const float ea = __expf(ay * rq);
  const float vyq = ea * frcp(row_sum16(ea));
  const float cy = bs4.x * (vyq      - vyk * rk) * rk;
  const float cq = bs4.y * (vqq * rq - vqk * rk) * rk;
  const float ck = bs4.z * (vkq * rq - vkk * rk) * rk;
  const float cb = bs4.w * (vbq * rq - vbk * rk) * rk;
  const float ks[16] = {ka.x, ka.y, ka.z, ka.w, kb.x, kb.y, kb.z, kb.w,
                        kc.x, kc.y, kc.z, kc.w, kd.x, kd.y, kd.z, kd.w};
#pragma unroll
  for (int j = 0; j < 16; ++j) {
    wy[j] += cy * ks[j]; wq[j] += cq * ks[j]; wk[j] += ck * ks[j]; wbr[j] += cb * ks[j];
  }
  return y;
}

// ---------------- embed: patchify + one-hot concat + linear ----------------
__global__ __launch_bounds__(256) void k_embed(const float* __restrict__ x,
                                               const int* __restrict__ fb,
                                               const float* __restrict__ inW,
                                               const float* __restrict__ inb,
                                               float* __restrict__ h) {
  const int blk = blockIdx.x;
  const int p  = blk & 15;
  const int sb = blk >> 4;
  const int ph = p >> 2, pw = p & 3;
  __shared__ float sx[cPD];
  const int t = threadIdx.x;
  if (t < cPD) {
    const int p1 = t / 7, p2 = t % 7;
    sx[t] = x[(size_t)sb * 784 + (ph * 7 + p1) * 28 + (pw * 7 + p2)];
  }
  __syncthreads();
  const int cls = fb[sb];
  float acc = inb[t] + inW[(size_t)(cPD + cls) * cD + t];
#pragma unroll
  for (int j = 0; j < cPD; ++j) acc += sx[j] * inW[(size_t)j * cD + t];
  h[((size_t)sb * cP + p) * cD + t] = acc;
}

// --------- token SRWM: 256 blocks x 128 threads (all 256 CUs) --------------
__global__ __launch_bounds__(128) void k_tok_srwm(
    float* __restrict__ h, const float* __restrict__ Wy0, const float* __restrict__ Wq0,
    const float* __restrict__ Wk0, const float* __restrict__ wb0,
    const float* __restrict__ lng, const float* __restrict__ lnb) {
  const int t    = threadIdx.x;
  const int lane = t & 63;
  const int w    = t >> 6;              // 0..1
  const int r    = lane & 15;
  const int li   = lane >> 4;
  const int b    = blockIdx.x >> 5;     // 8 b x 32 dgroups
  const int d    = ((blockIdx.x & 31) << 3) + (w << 2) + li;
  __shared__ __align__(16) float gscr[8][GSTR];
  float* gl = gscr[t >> 4];
  float wy[16], wq[16], wk[16], wbr[16];
#pragma unroll
  for (int j = 0; j < 16; ++j) {
    wy[j]  = Wy0[r * 16 + j];
    wq[j]  = Wq0[r * 16 + j];
    wk[j]  = Wk0[r * 16 + j];
    wbr[j] = wb0[(r & 3) * 16 + j];
  }
  const float gg = lng[r], bb = lnb[r];
  float xp[16];
#pragma unroll
  for (int s = 0; s < 16; ++s)
    xp[s] = h[((size_t)(s * cB + b) * cP + r) * cD + d];
  srwm_prestage(xp, gl, r);
  for (int s = 0; s < cS; ++s) {
    const float y = srwm_step(wy, wq, wk, wbr, gl, r, s);
    const float s1 = row_sum16(y);
    const float s2 = row_sum16(y * y);
    const float m = s1 * 0.0625f;
    const float var = s2 * 0.0625f - m * m;
    h[((size_t)(s * cB + b) * cP + r) * cD + d] = (y - m) * rsqrtf(var + LEPS) * gg + bb;
  }
}

// ---------------- token mixer: LN(D) then FFN over patch axis --------------
// R9: W1 transpose-staged to [e][pp] so the e-loop reads weights as float4
// LDS broadcasts (8 x b128 per e instead of 32 scalar ds_read_b32); b1
// staged to LDS. Cuts ~1.5k DS-issue cycles per dispatch.
__global__ __launch_bounds__(256) void k_tok_mixer(
    float* __restrict__ h, const float* __restrict__ g, const float* __restrict__ bta,
    const float* __restrict__ W1, const float* __restrict__ b1,
    const float* __restrict__ W2, const float* __restrict__ b2) {
  const int sb = blockIdx.x;
  const int t = threadIdx.x;
  __shared__ float tile[16][256];
  __shared__ __align__(16) float W1t[64 * 16];   // transposed: [e][pp]
  __shared__ __align__(16) float W2s[64 * 16];   // native:     [e][pp]
  __shared__ float b1s[64];
  __shared__ float mean_[16], rstd_[16];
  __shared__ float red[16][17], red2[16][17];
  const size_t base = (size_t)sb * cP * cD;
#pragma unroll
  for (int p = 0; p < 16; ++p) tile[p][t] = h[base + p * 256 + t];
#pragma unroll
  for (int kk = 0; kk < 4; ++kk) {
    const int idx = t + kk * 256;                 // idx = pp*64 + e
    W1t[(idx & 63) * 16 + (idx >> 6)] = W1[idx];  // -> [e][pp]
    W2s[idx] = W2[idx];                           // already [e][pp]
  }
  if (t < 64) b1s[t] = b1[t];
  __syncthreads();
  const int p = t >> 4, l = t & 15;
  float ps = 0.f, ps2 = 0.f;
#pragma unroll
  for (int k = 0; k < 16; ++k) { const float v = tile[p][l + 16 * k]; ps += v; ps2 += v * v; }
  red[p][l] = ps; red2[p][l] = ps2;
  __syncthreads();
  if (t < 16) {
    float sm = 0.f, s2 = 0.f;
#pragma unroll
    for (int k = 0; k < 16; ++k) { sm += red[t][k]; s2 += red2[t][k]; }
    const float m = sm * (1.f / 256.f);
    mean_[t] = m;
    rstd_[t] = rsqrtf(s2 * (1.f / 256.f) - m * m + LEPS);
  }
  __syncthreads();
  const float gd = g[t], bd = bta[t];
  float v[16], out[16];
#pragma unroll
  for (int pp = 0; pp < 16; ++pp) {
    v[pp] = (tile[pp][t] - mean_[pp]) * rstd_[pp] * gd + bd;
    out[pp] = b2[pp];
  }
  const float4* W1t4 = (const float4*)W1t;
  const float4* W2s4 = (const float4*)W2s;
  for (int e = 0; e < 64; ++e) {
    const float4 wa = W1t4[e * 4];
    const float4 wb = W1t4[e * 4 + 1];
    const float4 wc = W1t4[e * 4 + 2];
    const float4 wd = W1t4[e * 4 + 3];
    float a0 = v[0]  * wa.x + v[1]  * wa.y + v[2]  * wa.z + v[3]  * wa.w;
    float a1 = v[4]  * wb.x + v[5]  * wb.y + v[6]  * wb.z + v[7]  * wb.w;
    float a2 = v[8]  * wc.x + v[9]  * wc.y + v[10] * wc.z + v[11] * wc.w;
    float a3 = v[12] * wd.x + v[13] * wd.y + v[14] * wd.z + v[15] * wd.w;
    const float ge = gelu_t(b1s[e] + (a0 + a1) + (a2 + a3));
    const float4 u0 = W2s4[e * 4];
    const float4 u1 = W2s4[e * 4 + 1];
    const float4 u2 = W2s4[e * 4 + 2];
    const float4 u3 = W2s4[e * 4 + 3];
    out[0]  += ge * u0.x; out[1]  += ge * u0.y; out[2]  += ge * u0.z; out[3]  += ge * u0.w;
    out[4]  += ge * u1.x; out[5]  += ge * u1.y; out[6]  += ge * u1.z; out[7]  += ge * u1.w;
    out[8]  += ge * u2.x; out[9]  += ge * u2.y; out[10] += ge * u2.z; out[11] += ge * u2.w;
    out[12] += ge * u3.x; out[13] += ge * u3.y; out[14] += ge * u3.z; out[15] += ge * u3.w;
  }
#pragma unroll
  for (int pp = 0; pp < 16; ++pp) h[base + pp * 256 + t] = tile[pp][t] + out[pp];
}

// --------- channel SRWM scan: 256 blocks x 128 threads (8 heads each) ------
__global__ __launch_bounds__(128) void k_ch_scan(
    const float* __restrict__ h, float* __restrict__ y2,
    const float* __restrict__ Wy0, const float* __restrict__ Wq0,
    const float* __restrict__ Wk0, const float* __restrict__ wb0) {
  const int t  = threadIdx.x;
  const int hg = blockIdx.x & 1;        // head group (0: heads 0-7, 1: 8-15)
  const int bp = blockIdx.x >> 1;       // (b,p) instance
  const int hh = (hg << 3) + (t >> 4);  // global head
  const int r  = t & 15;
  const int d  = (hg << 7) + t;         // = hh*16 + r
  __shared__ __align__(16) float gscr[8][GSTR];
  float* gl = gscr[t >> 4];
  float wy[16], wq[16], wk[16], wbr[16];
#pragma unroll
  for (int j = 0; j < 16; ++j) {
    wy[j]  = Wy0[(hh * 16 + r) * 16 + j];
    wq[j]  = Wq0[(hh * 16 + r) * 16 + j];
    wk[j]  = Wk0[(hh * 16 + r) * 16 + j];
    wbr[j] = wb0[(hh * 4 + (r & 3)) * 16 + j];
  }
  float xp[16];
#pragma unroll
  for (int s = 0; s < 16; ++s)
    xp[s] = h[(size_t)(s * cB * cP + bp) * cD + d];
  srwm_prestage(xp, gl, r);
  for (int s = 0; s < cS; ++s)
    y2[(size_t)(s * cB * cP + bp) * cD + d] = srwm_step(wy, wq, wk, wbr, gl, r, s);
}

// --------- channel LN1 + mixer: 256 blocks x 512 threads, 8 rows each ------
__global__ __launch_bounds__(512) void k_ch_ln_mix(
    const float* __restrict__ y2, float* __restrict__ h,
    const float* __restrict__ lng, const float* __restrict__ lnb,
    const float* __restrict__ mg, const float* __restrict__ mb,
    const float* __restrict__ W1, const float* __restrict__ b1,
    const float* __restrict__ W2, const float* __restrict__ b2) {
  const int u = threadIdx.x;
  const int t = u & 255;
  const int jh = u >> 8;                // 0/1: which half of the k-loop
  const int row0 = blockIdx.x * 8;
  __shared__ float yv[8][256];          // rows; reused as W2-partial buffer
  __shared__ float lnv[8][256];
  __shared__ float hid[8][128];
  __shared__ float part1[8][128];
  // cooperative load of 8 consecutive rows (2048 consecutive floats)
  const float4* yp4 = (const float4*)(y2 + (size_t)row0 * cD);
  ((float4*)yv)[u] = yp4[u];
  __syncthreads();
  const int r32 = t >> 5, l = t & 31;
  float4 a0, a1;   // SRWM-LN output (mixer residual input), jh==0 only
  if (jh == 0) {
    const float4 eg0 = ((const float4*)lng)[l * 2];
    const float4 eg1 = ((const float4*)lng)[l * 2 + 1];
    const float4 eb0 = ((const float4*)lnb)[l * 2];
    const float4 eb1 = ((const float4*)lnb)[l * 2 + 1];
    const float4 mg0 = ((const float4*)mg)[l * 2];
    const float4 mg1 = ((const float4*)mg)[l * 2 + 1];
    const float4 mb0 = ((const float4*)mb)[l * 2];
    const float4 mb1 = ((const float4*)mb)[l * 2 + 1];
    const float4 y0 = ((const float4*)yv[r32])[l * 2];
    const float4 y1 = ((const float4*)yv[r32])[l * 2 + 1];
    float s1 = y0.x + y0.y + y0.z + y0.w + y1.x + y1.y + y1.z + y1.w;
    float s2 = y0.x * y0.x + y0.y * y0.y + y0.z * y0.z + y0.w * y0.w +
               y1.x * y1.x + y1.y * y1.y + y1.z * y1.z + y1.w * y1.w;
#pragma unroll
    for (int o = 1; o < 32; o <<= 1) {
      s1 += __shfl_xor(s1, o, 32);
      s2 += __shfl_xor(s2, o, 32);
    }
    const float m1 = s1 * (1.f / 256.f);
    const float rst1 = rsqrtf(s2 * (1.f / 256.f) - m1 * m1 + LEPS);
    a0.x = (y0.x - m1) * rst1 * eg0.x + eb0.x; a0.y = (y0.y - m1) * rst1 * eg0.y + eb0.y;
    a0.z = (y0.z - m1) * rst1 * eg0.z + eb0.z; a0.w = (y0.w - m1) * rst1 * eg0.w + eb0.w;
    a1.x = (y1.x - m1) * rst1 * eg1.x + eb1.x; a1.y = (y1.y - m1) * rst1 * eg1.y + eb1.y;
    a1.z = (y1.z - m1) * rst1 * eg1.z + eb1.z; a1.w = (y1.w - m1) * rst1 * eg1.w + eb1.w;
    float u1 = a0.x + a0.y + a0.z + a0.w + a1.x + a1.y + a1.z + a1.w;
    float u2 = a0.x * a0.x + a0.y * a0.y + a0.z * a0.z + a0.w * a0.w +
               a1.x * a1.x + a1.y * a1.y + a1.z * a1.z + a1.w * a1.w;
#pragma unroll
    for (int o = 1; o < 32; o <<= 1) {
      u1 += __shfl_xor(u1, o, 32);
      u2 += __shfl_xor(u2, o, 32);
    }
    const float m2 = u1 * (1.f / 256.f);
    const float rst2 = rsqrtf(u2 * (1.f / 256.f) - m2 * m2 + LEPS);
    float4 L0, L1;
    L0.x = (a0.x - m2) * rst2 * mg0.x + mb0.x; L0.y = (a0.y - m2) * rst2 * mg0.y + mb0.y;
    L0.z = (a0.z - m2) * rst2 * mg0.z + mb0.z; L0.w = (a0.w - m2) * rst2 * mg0.w + mb0.w;
    L1.x = (a1.x - m2) * rst2 * mg1.x + mb1.x; L1.y = (a1.y - m2) * rst2 * mg1.y + mb1.y;
    L1.z = (a1.z - m2) * rst2 * mg1.z + mb1.z; L1.w = (a1.w - m2) * rst2 * mg1.w + mb1.w;
    ((float4*)lnv[r32])[l * 2]     = L0;
    ((float4*)lnv[r32])[l * 2 + 1] = L1;
  }
  __syncthreads();
  // ---- W1 GEMV: hid = gelu(lnv @ W1 + b1), j-loop split across halves ----
  {
    const float4* W1f = (const float4*)W1;
    float4 acc;
    if (jh == 0) acc = ((const float4*)b1)[l];
    else         acc = make_float4(0.f, 0.f, 0.f, 0.f);
    const float4* xrow = (const float4*)lnv[r32];
    for (int j4 = jh * 32; j4 < jh * 32 + 32; ++j4) {
      const float4 xv = xrow[j4];
      const int j = j4 * 4;
      const float4 w0 = W1f[(j + 0) * 32 + l];
      const float4 w1 = W1f[(j + 1) * 32 + l];
      const float4 w2 = W1f[(j + 2) * 32 + l];
      const float4 w3 = W1f[(j + 3) * 32 + l];
      acc.x += xv.x * w0.x + xv.y * w1.x + xv.z * w2.x + xv.w * w3.x;
      acc.y += xv.x * w0.y + xv.y * w1.y + xv.z * w2.y + xv.w * w3.y;
      acc.z += xv.x * w0.z + xv.y * w1.z + xv.z * w2.z + xv.w * w3.z;
      acc.w += xv.x * w0.w + xv.y * w1.w + xv.z * w2.w + xv.w * w3.w;
    }
    if (jh == 1) ((float4*)part1[r32])[l] = acc;
    __syncthreads();
    if (jh == 0) {
      const float4 p = ((const float4*)part1[r32])[l];
      float4 hv;
      hv.x = gelu_t(acc.x + p.x); hv.y = gelu_t(acc.y + p.y);
      hv.z = gelu_t(acc.z + p.z); hv.w = gelu_t(acc.w + p.w);
      ((float4*)hid[r32])[l] = hv;
    }
    __syncthreads();
  }
  // ---- W2 GEMV: out = hid @ W2 + b2 (+residual), e-loop split ----
  {
    const float4* W2f = (const float4*)W2;
    float4 o0, o1;
    if (jh == 0) { o0 = ((const float4*)b2)[l * 2]; o1 = ((const float4*)b2)[l * 2 + 1]; }
    else         { o0 = make_float4(0.f, 0.f, 0.f, 0.f); o1 = o0; }
    const float4* hrow = (const float4*)hid[r32];
    for (int e4 = jh * 16; e4 < jh * 16 + 16; ++e4) {
      const float4 xh = hrow[e4];
      const int e = e4 * 4;
#pragma unroll
      for (int ee = 0; ee < 4; ++ee) {
        const float xv = (ee == 0) ? xh.x : (ee == 1) ? xh.y : (ee == 2) ? xh.z : xh.w;
        const float4 w0 = W2f[(e + ee) * 64 + l * 2];
        const float4 w1 = W2f[(e + ee) * 64 + l * 2 + 1];
        o0.x += xv * w0.x; o0.y += xv * w0.y; o0.z += xv * w0.z; o0.w += xv * w0.w;
        o1.x += xv * w1.x; o1.y += xv * w1.y; o1.z += xv * w1.z; o1.w += xv * w1.w;
      }
    }
    if (jh == 1) {
      ((float4*)yv[r32])[l * 2]     = o0;   // yv dead: reuse as partial buf
      ((float4*)yv[r32])[l * 2 + 1] = o1;
    }
    __syncthreads();
    if (jh == 0) {
      const float4 p0 = ((const float4*)yv[r32])[l * 2];
      const float4 p1 = ((const float4*)yv[r32])[l * 2 + 1];
      o0.x += p0.x + a0.x; o0.y += p0.y + a0.y; o0.z += p0.z + a0.z; o0.w += p0.w + a0.w;
      o1.x += p1.x + a1.x; o1.y += p1.y + a1.y; o1.z += p1.z + a1.z; o1.w += p1.w + a1.w;
      float4* op = (float4*)(h + ((size_t)row0 + r32) * cD);
      op[l * 2]     = o0;
      op[l * 2 + 1] = o1;
    }
  }
}

// ---------------- final LN + mean over patches -----------------------------
__global__ __launch_bounds__(256) void k_fln_mean(
    const float* __restrict__ h, const float* __restrict__ gg, const float* __restrict__ bbv,
    float* __restrict__ o) {
  const int sb = blockIdx.x;
  const int t = threadIdx.x;
  const int lane = t & 63, w = t >> 6;
  const float4 g4 = ((const float4*)gg)[lane];
  const float4 b4 = ((const float4*)bbv)[lane];
  float a0 = 0.f, a1 = 0.f, a2 = 0.f, a3 = 0.f;
  for (int pp = 0; pp < 4; ++pp) {
    const int p = w * 4 + pp;
    const float4 v4 = ((const float4*)(h + ((size_t)sb * cP + p) * cD))[lane];
    const float s1 = wave_sum64(v4.x + v4.y + v4.z + v4.w);
    const float s2 = wave_sum64(v4.x * v4.x + v4.y * v4.y + v4.z * v4.z + v4.w * v4.w);
    const float m = s1 * (1.f / 256.f);
    const float rst = rsqrtf(s2 * (1.f / 256.f) - m * m + LEPS);
    a0 += (v4.x - m) * rst * g4.x + b4.x;
    a1 += (v4.y - m) * rst * g4.y + b4.y;
    a2 += (v4.z - m) * rst * g4.z + b4.z;
    a3 += (v4.w - m) * rst * g4.w + b4.w;
  }
  __shared__ float sacc[4][256];
  float4* sp = (float4*)sacc[w];
  sp[lane] = make_float4(a0, a1, a2, a3);
  __syncthreads();
  o[(size_t)sb * cD + t] = (sacc[0][t] + sacc[1][t] + sacc[2][t] + sacc[3][t]) * (1.f / 16.f);
}

// -------- output SRWM: barrier-free scan + batched LN/projection ----------
__global__ __launch_bounds__(256, 1) void k_out_srwm(
    const float* __restrict__ gin, float* __restrict__ outp,
    const float* __restrict__ Wy0, const float* __restrict__ Wq0,
    const float* __restrict__ Wk0, const float* __restrict__ wb0,
    const float* __restrict__ lng, const float* __restrict__ lnb,
    const float* __restrict__ outW, const float* __restrict__ outb) {
  const int t = threadIdx.x;
  const int lane = t & 63;
  const int w = t >> 6;
  const int hh = t >> 4, r = t & 15;
  const int b = blockIdx.x;
  __shared__ float ymat[16][256];
  __shared__ float gwm[cNC][256];
  __shared__ float GBp[4][10];
  __shared__ float GBs[10];
  __shared__ __align__(16) float gscr[16][GSTR];
  float* gl = gscr[hh];
  float wy[16], wq[16], wk[16], wbr[16];
#pragma unroll
  for (int j = 0; j < 16; ++j) {
    wy[j]  = Wy0[(hh * 16 + r) * 16 + j];
    wq[j]  = Wq0[(hh * 16 + r) * 16 + j];
    wk[j]  = Wk0[(hh * 16 + r) * 16 + j];
    wbr[j] = wb0[(hh * 4 + (r & 3)) * 16 + j];
  }
  {
    const float gg = lng[t], bbl = lnb[t];
    float pg[cNC], pbv[cNC];
#pragma unroll
    for (int c = 0; c < cNC; ++c) {
      const float wv = outW[(size_t)t * cNC + c];
      const float gwv = gg * wv;
      gwm[c][t] = gwv;
      pg[c] = wave_sum64(gwv);
      pbv[c] = wave_sum64(bbl * wv);
    }
    if (lane == 0) {
#pragma unroll
      for (int c = 0; c < cNC; ++c) { GBp[w][c] = pg[c]; GBp[w][5 + c] = pbv[c]; }
    }
    __syncthreads();
    if (t < 10) GBs[t] = GBp[0][t] + GBp[1][t] + GBp[2][t] + GBp[3][t];
    __syncthreads();
  }
  float xp[16];
#pragma unroll
  for (int s = 0; s < 16; ++s) xp[s] = gin[(size_t)(s * cB + b) * cD + t];
  srwm_prestage(xp, gl, r);
  for (int s = 0; s < cS; ++s)
    ymat[s][t] = srwm_step(wy, wq, wk, wbr, gl, r, s);
  __syncthreads();
  for (int k2 = 0; k2 < 4; ++k2) {
    const int sidx = w * 4 + k2;
    const float4 y4 = ((const float4*)ymat[sidx])[lane];
    const float s1 = wave_sum64(y4.x + y4.y + y4.z + y4.w);
    const float s2 = wave_sum64(y4.x * y4.x + y4.y * y4.y + y4.z * y4.z + y4.w * y4.w);
    float S[cNC];
#pragma unroll
    for (int c = 0; c < cNC; ++c) {
      const float4 g4 = ((const float4*)gwm[c])[lane];
      S[c] = wave_sum64(y4.x * g4.x + y4.y * g4.y + y4.z * g4.z + y4.w * g4.w);
    }
    if (lane == 0) {
      const float m = s1 * (1.f / 256.f);
      const float var = s2 * (1.f / 256.f) - m * m;
      const float rst = rsqrtf(var + LEPS);
#pragma unroll
      for (int c = 0; c < cNC; ++c) {
        outp[(size_t)(sidx * cB + b) * cNC + c] =
            outb[c] + rst * S[c] - rst * m * GBs[c] + GBs[5 + c];
      }
    }
  }
}

extern "C" void kernel_launch(void* const* d_in, const int* in_sizes, int n_in,
                              void* d_out, int out_size, void* d_ws, size_t ws_size,
                              hipStream_t stream) {
  const float* x     = (const float*)d_in[0];
  const int*   fb    = (const int*)d_in[1];
  const float* inW   = (const float*)d_in[2];
  const float* inb   = (const float*)d_in[3];
  const float* tkWy  = (const float*)d_in[4];
  const float* tkWq  = (const float*)d_in[5];
  const float* tkWk  = (const float*)d_in[6];
  const float* tkwb  = (const float*)d_in[7];
  const float* tklng = (const float*)d_in[8];
  const float* tklnb = (const float*)d_in[9];
  const float* tkmg  = (const float*)d_in[10];
  const float* tkmb  = (const float*)d_in[11];
  const float* tkmW1 = (const float*)d_in[12];
  const float* tkmb1 = (const float*)d_in[13];
  const float* tkmW2 = (const float*)d_in[14];
  const float* tkmb2 = (const float*)d_in[15];
  const float* chWy  = (const float*)d_in[16];
  const float* chWq  = (const float*)d_in[17];
  const float* chWk  = (const float*)d_in[18];
  const float* chwb  = (const float*)d_in[19];
  const float* chlng = (const float*)d_in[20];
  const float* chlnb = (const float*)d_in[21];
  const float* chmg  = (const float*)d_in[22];
  const float* chmb  = (const float*)d_in[23];
  const float* chmW1 = (const float*)d_in[24];
  const float* chmb1 = (const float*)d_in[25];
  const float* chmW2 = (const float*)d_in[26];
  const float* chmb2 = (const float*)d_in[27];
  const float* flng  = (const float*)d_in[28];
  const float* flnb  = (const float*)d_in[29];
  const float* oWy   = (const float*)d_in[30];
  const float* oWq   = (const float*)d_in[31];
  const float* oWk   = (const float*)d_in[32];
  const float* owb   = (const float*)d_in[33];
  const float* olng  = (const float*)d_in[34];
  const float* olnb  = (const float*)d_in[35];
  const float* outW  = (const float*)d_in[36];
  const float* outb  = (const float*)d_in[37];

  float* h    = (float*)d_ws;                               // (S,B,P,D) 2 MB
  float* gbuf = h + (size_t)cS * cB * cP * cD;              // (S,B,D)
  float* y2   = gbuf + (size_t)cS * cB * cD;                // (S,B,P,D) 2 MB scratch
  float* outp = (float*)d_out;                              // (S,B,NC)

  k_embed<<<dim3(cS * cB * cP), dim3(256), 0, stream>>>(x, fb, inW, inb, h);
  for (int i = 0; i < 2; ++i) {
    k_tok_srwm<<<dim3(256), dim3(128), 0, stream>>>(
        h, tkWy + i * 256, tkWq + i * 256, tkWk + i * 256, tkwb + i * 64,
        tklng + i * 16, tklnb + i * 16);
    k_tok_mixer<<<dim3(cS * cB), dim3(256), 0, stream>>>(
        h, tkmg + i * 256, tkmb + i * 256, tkmW1 + i * 1024, tkmb1 + i * 64,
        tkmW2 + i * 1024, tkmb2 + i * 16);
    k_ch_scan<<<dim3(cB * cP * 2), dim3(128), 0, stream>>>(
        h, y2, chWy + i * 4096, chWq + i * 4096, chWk + i * 4096, chwb + i * 1024);
    k_ch_ln_mix<<<dim3(cS * cB * cP / 8), dim3(512), 0, stream>>>(
        y2, h, chlng + i * 256, chlnb + i * 256,
        chmg + i * 256, chmb + i * 256, chmW1 + i * 32768, chmb1 + i * 128,
        chmW2 + i * 32768, chmb2 + i * 256);
  }
  k_fln_mean<<<dim3(cS * cB), dim3(256), 0, stream>>>(h, flng, flnb, gbuf);
  k_out_srwm<<<dim3(cB), dim3(256), 0, stream>>>(
      gbuf, outp, oWy, oWq, oWk, owb, olng, olnb, outW, outb);
}

// Round 10
// 294.315 us; speedup vs baseline: 1.0711x; 1.0319x over previous
//
#include <hip/hip_runtime.h>
#include <math.h>

// Problem constants (from reference)
constexpr int cS  = 16;   // sequence
constexpr int cB  = 8;    // batch
constexpr int cNC = 5;    // classes
constexpr int cD  = 256;  // hidden
constexpr int cP  = 16;   // patches
constexpr int cPD = 49;   // patch dim
#define LEPS 1e-5f
// per-group scan scratch stride (floats): x[16][16] + eq[16]+ek[16]+bsig[16]
// = 304, padded to 328 (328%32==8 -> 2-way-free bank pattern, 16B aligned)
#define GSTR 328

__device__ __forceinline__ float frcp(float x) { return __builtin_amdgcn_rcpf(x); }
__device__ __forceinline__ float sigm(float x) { return frcp(1.0f + __expf(-x)); }
__device__ __forceinline__ float gelu_t(float x) {
  const float z = 1.5957691216057308f * (x + 0.044715f * x * x * x);
  return x * frcp(1.0f + __expf(-z));
}

template<int CTRL>
__device__ __forceinline__ float dpp_mov(float v) {
  return __int_as_float(__builtin_amdgcn_update_dpp(
      0, __float_as_int(v), CTRL, 0xF, 0xF, true));
}
__device__ __forceinline__ float row_sum16(float v) {
  v += dpp_mov<0xB1>(v);   // quad_perm [1,0,3,2]
  v += dpp_mov<0x4E>(v);   // quad_perm [2,3,0,1]
  v += dpp_mov<0x124>(v);  // row_ror:4
  v += dpp_mov<0x128>(v);  // row_ror:8
  return v;
}
__device__ __forceinline__ float wave_sum64(float v) {
  v = row_sum16(v);
  v += __shfl_xor(v, 16, 64);
  v += __shfl_xor(v, 32, 64);
  return v;
}

// 16-dot with 4-way split chains (4-deep FMA chains + tree).
__device__ __forceinline__ float dot16(const float (&w)[16],
    const float4 a, const float4 b, const float4 c, const float4 d) {
  float s0 = w[0]  * a.x; s0 += w[1]  * a.y; s0 += w[2]  * a.z; s0 += w[3]  * a.w;
  float s1 = w[4]  * b.x; s1 += w[5]  * b.y; s1 += w[6]  * b.z; s1 += w[7]  * b.w;
  float s2 = w[8]  * c.x; s2 += w[9]  * c.y; s2 += w[10] * c.z; s2 += w[11] * c.w;
  float s3 = w[12] * d.x; s3 += w[13] * d.y; s3 += w[14] * d.z; s3 += w[15] * d.w;
  return (s0 + s1) + (s2 + s3);
}

// ---- scan prologue: pre-broadcast all 16 x-vectors into group scratch ----
// x is scan-independent, so the per-step x write+barrier round-trip is hoisted
// out of the serial chain entirely (R7, verified -6.3 us). One wave_barrier
// covers all writes.
__device__ __forceinline__ void srwm_prestage(
    const float (&xp)[16], float* gl, const int r) {
#pragma unroll
  for (int s = 0; s < 16; ++s) gl[s * 16 + r] = xp[s];
  __builtin_amdgcn_wave_barrier();
}

// ---- SRWM step, pre-staged x: only ONE LDS round-trip (eq/ek/bsig) on the
// ---- per-step critical path. Wave-internal DS ordering is in-order.
__device__ __forceinline__ float srwm_step(
    float (&wy)[16], float (&wq)[16], float (&wk)[16], float (&wbr)[16],
    float* gl, const int r, const int s) {
  const float4* xg = (const float4*)(gl + s * 16);
  const float4 xa = xg[0], xb = xg[1], xc = xg[2], xd = xg[3];
  const float y  = dot16(wy,  xa, xb, xc, xd);
  const float q  = dot16(wq,  xa, xb, xc, xd);
  const float k  = dot16(wk,  xa, xb, xc, xd);
  const float bt = dot16(wbr, xa, xb, xc, xd);
  const float bsig = sigm(bt);
  const float eq = __expf(q), ek = __expf(k);
  gl[256 + r] = eq;
  gl[272 + r] = ek;
  gl[288 + r] = bsig;
  __builtin_amdgcn_wave_barrier();
  const float4* g4 = (const float4*)(gl + 256);
  const float4 qa = g4[0], qb = g4[1], qc = g4[2], qd = g4[3];
  const float4 ka = g4[4], kb = g4[5], kc = g4[6], kd = g4[7];
  const float4 bs4 = g4[8];
  const float ay  = dot16(wy,  qa, qb, qc, qd);
  const float vqq = dot16(wq,  qa, qb, qc, qd);
  const float vkq = dot16(wk,  qa, qb, qc, qd);
  const float vbq = dot16(wbr, qa, qb, qc, qd);
  const float vyk = dot16(wy,  ka, kb, kc, kd);
  const float vqk = dot16(wq,  ka, kb, kc, kd);
  const float vkk = dot16(wk,  ka, kb, kc, kd);
  const float vbk = dot16(wbr, ka, kb, kc, kd);
  const float sq = ((qa.x + qa.y) + (qa.z + qa.w)) + ((qb.x + qb.y) + (qb.z + qb.w))
                 + ((qc.x + qc.y) + (qc.z + qc.w)) + ((qd.x + qd.y) + (qd.z + qd.w));
  const float sk = ((ka.x + ka.y) + (ka.z + ka.w)) + ((kb.x + kb.y) + (kb.z + kb.w))
                 + ((kc.x + kc.y) + (kc.z + kc.w)) + ((kd.x + kd.y) + (kd.z + kd.w));
  const float rq = frcp(sq);
  const float rk = frcp(sk);
  const float ea = __expf(ay * rq);
  const float vyq = ea * frcp(row_sum16(ea));
  const float cy = bs4.x * (vyq      - vyk * rk) * rk;
  const float cq = bs4.y * (vqq * rq - vqk * rk) * rk;
  const float ck = bs4.z * (vkq * rq - vkk * rk) * rk;
  const float cb = bs4.w * (vbq * rq - vbk * rk) * rk;
  const float ks[16] = {ka.x, ka.y, ka.z, ka.w, kb.x, kb.y, kb.z, kb.w,
                        kc.x, kc.y, kc.z, kc.w, kd.x, kd.y, kd.z, kd.w};
#pragma unroll
  for (int j = 0; j < 16; ++j) {
    wy[j] += cy * ks[j]; wq[j] += cq * ks[j]; wk[j] += ck * ks[j]; wbr[j] += cb * ks[j];
  }
  return y;
}

// ---------------- embed: patchify + one-hot concat + linear ----------------
__global__ __launch_bounds__(256) void k_embed(const float* __restrict__ x,
                                               const int* __restrict__ fb,
                                               const float* __restrict__ inW,
                                               const float* __restrict__ inb,
                                               float* __restrict__ h) {
  const int blk = blockIdx.x;
  const int p  = blk & 15;
  const int sb = blk >> 4;
  const int ph = p >> 2, pw = p & 3;
  __shared__ float sx[cPD];
  const int t = threadIdx.x;
  if (t < cPD) {
    const int p1 = t / 7, p2 = t % 7;
    sx[t] = x[(size_t)sb * 784 + (ph * 7 + p1) * 28 + (pw * 7 + p2)];
  }
  __syncthreads();
  const int cls = fb[sb];
  float acc = inb[t] + inW[(size_t)(cPD + cls) * cD + t];
#pragma unroll
  for (int j = 0; j < cPD; ++j) acc += sx[j] * inW[(size_t)j * cD + t];
  h[((size_t)sb * cP + p) * cD + t] = acc;
}

// --------- token SRWM: 256 blocks x 128 threads (all 256 CUs) --------------
__global__ __launch_bounds__(128) void k_tok_srwm(
    float* __restrict__ h, const float* __restrict__ Wy0, const float* __restrict__ Wq0,
    const float* __restrict__ Wk0, const float* __restrict__ wb0,
    const float* __restrict__ lng, const float* __restrict__ lnb) {
  const int t    = threadIdx.x;
  const int lane = t & 63;
  const int w    = t >> 6;              // 0..1
  const int r    = lane & 15;
  const int li   = lane >> 4;
  const int b    = blockIdx.x >> 5;     // 8 b x 32 dgroups
  const int d    = ((blockIdx.x & 31) << 3) + (w << 2) + li;
  __shared__ __align__(16) float gscr[8][GSTR];
  float* gl = gscr[t >> 4];
  float wy[16], wq[16], wk[16], wbr[16];
#pragma unroll
  for (int j = 0; j < 16; ++j) {
    wy[j]  = Wy0[r * 16 + j];
    wq[j]  = Wq0[r * 16 + j];
    wk[j]  = Wk0[r * 16 + j];
    wbr[j] = wb0[(r & 3) * 16 + j];
  }
  const float gg = lng[r], bb = lnb[r];
  float xp[16];
#pragma unroll
  for (int s = 0; s < 16; ++s)
    xp[s] = h[((size_t)(s * cB + b) * cP + r) * cD + d];
  srwm_prestage(xp, gl, r);
  for (int s = 0; s < cS; ++s) {
    const float y = srwm_step(wy, wq, wk, wbr, gl, r, s);
    const float s1 = row_sum16(y);
    const float s2 = row_sum16(y * y);
    const float m = s1 * 0.0625f;
    const float var = s2 * 0.0625f - m * m;
    h[((size_t)(s * cB + b) * cP + r) * cD + d] = (y - m) * rsqrtf(var + LEPS) * gg + bb;
  }
}

// ---------------- token mixer: LN(D) then FFN over patch axis --------------
// (R7 form. R9's float4-broadcast e-loop + W1 transpose REGRESSED +14 us:
// the transpose staging write was a 2-bank conflict, and same-address scalar
// LDS broadcasts were never the cost. Keep the scalar-broadcast loop.)
__global__ __launch_bounds__(256) void k_tok_mixer(
    float* __restrict__ h, const float* __restrict__ g, const float* __restrict__ bta,
    const float* __restrict__ W1, const float* __restrict__ b1,
    const float* __restrict__ W2, const float* __restrict__ b2) {
  const int sb = blockIdx.x;
  const int t = threadIdx.x;
  __shared__ float tile[16][256];
  __shared__ float W1s[16 * 64], W2s[64 * 16];
  __shared__ float mean_[16], rstd_[16];
  __shared__ float red[16][17], red2[16][17];
  const size_t base = (size_t)sb * cP * cD;
#pragma unroll
  for (int p = 0; p < 16; ++p) tile[p][t] = h[base + p * 256 + t];
  W1s[t] = W1[t]; W1s[t + 256] = W1[t + 256]; W1s[t + 512] = W1[t + 512]; W1s[t + 768] = W1[t + 768];
  W2s[t] = W2[t]; W2s[t + 256] = W2[t + 256]; W2s[t + 512] = W2[t + 512]; W2s[t + 768] = W2[t + 768];
  __syncthreads();
  const int p = t >> 4, l = t & 15;
  float ps = 0.f, ps2 = 0.f;
#pragma unroll
  for (int k = 0; k < 16; ++k) { const float v = tile[p][l + 16 * k]; ps += v; ps2 += v * v; }
  red[p][l] = ps; red2[p][l] = ps2;
  __syncthreads();
  if (t < 16) {
    float sm = 0.f, s2 = 0.f;
#pragma unroll
    for (int k = 0; k < 16; ++k) { sm += red[t][k]; s2 += red2[t][k]; }
    const float m = sm * (1.f / 256.f);
    mean_[t] = m;
    rstd_[t] = rsqrtf(s2 * (1.f / 256.f) - m * m + LEPS);
  }
  __syncthreads();
  const float gd = g[t], bd = bta[t];
  float v[16], out[16];
#pragma unroll
  for (int pp = 0; pp < 16; ++pp) {
    v[pp] = (tile[pp][t] - mean_[pp]) * rstd_[pp] * gd + bd;
    out[pp] = b2[pp];
  }
  for (int e = 0; e < 64; ++e) {
    float acc = b1[e];
#pragma unroll
    for (int pp = 0; pp < 16; ++pp) acc += v[pp] * W1s[pp * 64 + e];
    const float ge = gelu_t(acc);
#pragma unroll
    for (int pp = 0; pp < 16; ++pp) out[pp] += ge * W2s[e * 16 + pp];
  }
#pragma unroll
  for (int pp = 0; pp < 16; ++pp) h[base + pp * 256 + t] = tile[pp][t] + out[pp];
}

// --------- channel SRWM scan: 256 blocks x 128 threads (8 heads each) ------
__global__ __launch_bounds__(128) void k_ch_scan(
    const float* __restrict__ h, float* __restrict__ y2,
    const float* __restrict__ Wy0, const float* __restrict__ Wq0,
    const float* __restrict__ Wk0, const float* __restrict__ wb0) {
  const int t  = threadIdx.x;
  const int hg = blockIdx.x & 1;        // head group (0: heads 0-7, 1: 8-15)
  const int bp = blockIdx.x >> 1;       // (b,p) instance
  const int hh = (hg << 3) + (t >> 4);  // global head
  const int r  = t & 15;
  const int d  = (hg << 7) + t;         // = hh*16 + r
  __shared__ __align__(16) float gscr[8][GSTR];
  float* gl = gscr[t >> 4];
  float wy[16], wq[16], wk[16], wbr[16];
#pragma unroll
  for (int j = 0; j < 16; ++j) {
    wy[j]  = Wy0[(hh * 16 + r) * 16 + j];
    wq[j]  = Wq0[(hh * 16 + r) * 16 + j];
    wk[j]  = Wk0[(hh * 16 + r) * 16 + j];
    wbr[j] = wb0[(hh * 4 + (r & 3)) * 16 + j];
  }
  float xp[16];
#pragma unroll
  for (int s = 0; s < 16; ++s)
    xp[s] = h[(size_t)(s * cB * cP + bp) * cD + d];
  srwm_prestage(xp, gl, r);
  for (int s = 0; s < cS; ++s)
    y2[(size_t)(s * cB * cP + bp) * cD + d] = srwm_step(wy, wq, wk, wbr, gl, r, s);
}

// --------- channel LN1 + mixer: 256 blocks x 512 threads, 8 rows each ------
__global__ __launch_bounds__(512) void k_ch_ln_mix(
    const float* __restrict__ y2, float* __restrict__ h,
    const float* __restrict__ lng, const float* __restrict__ lnb,
    const float* __restrict__ mg, const float* __restrict__ mb,
    const float* __restrict__ W1, const float* __restrict__ b1,
    const float* __restrict__ W2, const float* __restrict__ b2) {
  const int u = threadIdx.x;
  const int t = u & 255;
  const int jh = u >> 8;                // 0/1: which half of the k-loop
  const int row0 = blockIdx.x * 8;
  __shared__ float yv[8][256];          // rows; reused as W2-partial buffer
  __shared__ float lnv[8][256];
  __shared__ float hid[8][128];
  __shared__ float part1[8][128];
  // cooperative load of 8 consecutive rows (2048 consecutive floats)
  const float4* yp4 = (const float4*)(y2 + (size_t)row0 * cD);
  ((float4*)yv)[u] = yp4[u];
  __syncthreads();
  const int r32 = t >> 5, l = t & 31;
  float4 a0, a1;   // SRWM-LN output (mixer residual input), jh==0 only
  if (jh == 0) {
    const float4 eg0 = ((const float4*)lng)[l * 2];
    const float4 eg1 = ((const float4*)lng)[l * 2 + 1];
    const float4 eb0 = ((const float4*)lnb)[l * 2];
    const float4 eb1 = ((const float4*)lnb)[l * 2 + 1];
    const float4 mg0 = ((const float4*)mg)[l * 2];
    const float4 mg1 = ((const float4*)mg)[l * 2 + 1];
    const float4 mb0 = ((const float4*)mb)[l * 2];
    const float4 mb1 = ((const float4*)mb)[l * 2 + 1];
    const float4 y0 = ((const float4*)yv[r32])[l * 2];
    const float4 y1 = ((const float4*)yv[r32])[l * 2 + 1];
    float s1 = y0.x + y0.y + y0.z + y0.w + y1.x + y1.y + y1.z + y1.w;
    float s2 = y0.x * y0.x + y0.y * y0.y + y0.z * y0.z + y0.w * y0.w +
               y1.x * y1.x + y1.y * y1.y + y1.z * y1.z + y1.w * y1.w;
#pragma unroll
    for (int o = 1; o < 32; o <<= 1) {
      s1 += __shfl_xor(s1, o, 32);
      s2 += __shfl_xor(s2, o, 32);
    }
    const float m1 = s1 * (1.f / 256.f);
    const float rst1 = rsqrtf(s2 * (1.f / 256.f) - m1 * m1 + LEPS);
    a0.x = (y0.x - m1) * rst1 * eg0.x + eb0.x; a0.y = (y0.y - m1) * rst1 * eg0.y + eb0.y;
    a0.z = (y0.z - m1) * rst1 * eg0.z + eb0.z; a0.w = (y0.w - m1) * rst1 * eg0.w + eb0.w;
    a1.x = (y1.x - m1) * rst1 * eg1.x + eb1.x; a1.y = (y1.y - m1) * rst1 * eg1.y + eb1.y;
    a1.z = (y1.z - m1) * rst1 * eg1.z + eb1.z; a1.w = (y1.w - m1) * rst1 * eg1.w + eb1.w;
    float u1 = a0.x + a0.y + a0.z + a0.w + a1.x + a1.y + a1.z + a1.w;
    float u2 = a0.x * a0.x + a0.y * a0.y + a0.z * a0.z + a0.w * a0.w +
               a1.x * a1.x + a1.y * a1.y + a1.z * a1.z + a1.w * a1.w;
#pragma unroll
    for (int o = 1; o < 32; o <<= 1) {
      u1 += __shfl_xor(u1, o, 32);
      u2 += __shfl_xor(u2, o, 32);
    }
    const float m2 = u1 * (1.f / 256.f);
    const float rst2 = rsqrtf(u2 * (1.f / 256.f) - m2 * m2 + LEPS);
    float4 L0, L1;
    L0.x = (a0.x - m2) * rst2 * mg0.x + mb0.x; L0.y = (a0.y - m2) * rst2 * mg0.y + mb0.y;
    L0.z = (a0.z - m2) * rst2 * mg0.z + mb0.z; L0.w = (a0.w - m2) * rst2 * mg0.w + mb0.w;
    L1.x = (a1.x - m2) * rst2 * mg1.x + mb1.x; L1.y = (a1.y - m2) * rst2 * mg1.y + mb1.y;
    L1.z = (a1.z - m2) * rst2 * mg1.z + mb1.z; L1.w = (a1.w - m2) * rst2 * mg1.w + mb1.w;
    ((float4*)lnv[r32])[l * 2]     = L0;
    ((float4*)lnv[r32])[l * 2 + 1] = L1;
  }
  __syncthreads();
  // ---- W1 GEMV: hid = gelu(lnv @ W1 + b1), j-loop split across halves ----
  {
    const float4* W1f = (const float4*)W1;
    float4 acc;
    if (jh == 0) acc = ((const float4*)b1)[l];
    else         acc = make_float4(0.f, 0.f, 0.f, 0.f);
    const float4* xrow = (const float4*)lnv[r32];
    for (int j4 = jh * 32; j4 < jh * 32 + 32; ++j4) {
      const float4 xv = xrow[j4];
      const int j = j4 * 4;
      const float4 w0 = W1f[(j + 0) * 32 + l];
      const float4 w1 = W1f[(j + 1) * 32 + l];
      const float4 w2 = W1f[(j + 2) * 32 + l];
      const float4 w3 = W1f[(j + 3) * 32 + l];
      acc.x += xv.x * w0.x + xv.y * w1.x + xv.z * w2.x + xv.w * w3.x;
      acc.y += xv.x * w0.y + xv.y * w1.y + xv.z * w2.y + xv.w * w3.y;
      acc.z += xv.x * w0.z + xv.y * w1.z + xv.z * w2.z + xv.w * w3.z;
      acc.w += xv.x * w0.w + xv.y * w1.w + xv.z * w2.w + xv.w * w3.w;
    }
    if (jh == 1) ((float4*)part1[r32])[l] = acc;
    __syncthreads();
    if (jh == 0) {
      const float4 p = ((const float4*)part1[r32])[l];
      float4 hv;
      hv.x = gelu_t(acc.x + p.x); hv.y = gelu_t(acc.y + p.y);
      hv.z = gelu_t(acc.z + p.z); hv.w = gelu_t(acc.w + p.w);
      ((float4*)hid[r32])[l] = hv;
    }
    __syncthreads();
  }
  // ---- W2 GEMV: out = hid @ W2 + b2 (+residual), e-loop split ----
  {
    const float4* W2f = (const float4*)W2;
    float4 o0, o1;
    if (jh == 0) { o0 = ((const float4*)b2)[l * 2]; o1 = ((const float4*)b2)[l * 2 + 1]; }
    else         { o0 = make_float4(0.f, 0.f, 0.f, 0.f); o1 = o0; }
    const float4* hrow = (const float4*)hid[r32];
    for (int e4 = jh * 16; e4 < jh * 16 + 16; ++e4) {
      const float4 xh = hrow[e4];
      const int e = e4 * 4;
#pragma unroll
      for (int ee = 0; ee < 4; ++ee) {
        const float xv = (ee == 0) ? xh.x : (ee == 1) ? xh.y : (ee == 2) ? xh.z : xh.w;
        const float4 w0 = W2f[(e + ee) * 64 + l * 2];
        const float4 w1 = W2f[(e + ee) * 64 + l * 2 + 1];
        o0.x += xv * w0.x; o0.y += xv * w0.y; o0.z += xv * w0.z; o0.w += xv * w0.w;
        o1.x += xv * w1.x; o1.y += xv * w1.y; o1.z += xv * w1.z; o1.w += xv * w1.w;
      }
    }
    if (jh == 1) {
      ((float4*)yv[r32])[l * 2]     = o0;   // yv dead: reuse as partial buf
      ((float4*)yv[r32])[l * 2 + 1] = o1;
    }
    __syncthreads();
    if (jh == 0) {
      const float4 p0 = ((const float4*)yv[r32])[l * 2];
      const float4 p1 = ((const float4*)yv[r32])[l * 2 + 1];
      o0.x += p0.x + a0.x; o0.y += p0.y + a0.y; o0.z += p0.z + a0.z; o0.w += p0.w + a0.w;
      o1.x += p1.x + a1.x; o1.y += p1.y + a1.y; o1.z += p1.z + a1.z; o1.w += p1.w + a1.w;
      float4* op = (float4*)(h + ((size_t)row0 + r32) * cD);
      op[l * 2]     = o0;
      op[l * 2 + 1] = o1;
    }
  }
}

// ---------------- final LN + mean over patches -----------------------------
__global__ __launch_bounds__(256) void k_fln_mean(
    const float* __restrict__ h, const float* __restrict__ gg, const float* __restrict__ bbv,
    float* __restrict__ o) {
  const int sb = blockIdx.x;
  const int t = threadIdx.x;
  const int lane = t & 63, w = t >> 6;
  const float4 g4 = ((const float4*)gg)[lane];
  const float4 b4 = ((const float4*)bbv)[lane];
  float a0 = 0.f, a1 = 0.f, a2 = 0.f, a3 = 0.f;
  for (int pp = 0; pp < 4; ++pp) {
    const int p = w * 4 + pp;
    const float4 v4 = ((const float4*)(h + ((size_t)sb * cP + p) * cD))[lane];
    const float s1 = wave_sum64(v4.x + v4.y + v4.z + v4.w);
    const float s2 = wave_sum64(v4.x * v4.x + v4.y * v4.y + v4.z * v4.z + v4.w * v4.w);
    const float m = s1 * (1.f / 256.f);
    const float rst = rsqrtf(s2 * (1.f / 256.f) - m * m + LEPS);
    a0 += (v4.x - m) * rst * g4.x + b4.x;
    a1 += (v4.y - m) * rst * g4.y + b4.y;
    a2 += (v4.z - m) * rst * g4.z + b4.z;
    a3 += (v4.w - m) * rst * g4.w + b4.w;
  }
  __shared__ float sacc[4][256];
  float4* sp = (float4*)sacc[w];
  sp[lane] = make_float4(a0, a1, a2, a3);
  __syncthreads();
  o[(size_t)sb * cD + t] = (sacc[0][t] + sacc[1][t] + sacc[2][t] + sacc[3][t]) * (1.f / 16.f);
}

// -------- output SRWM: barrier-free scan + batched LN/projection ----------
__global__ __launch_bounds__(256, 1) void k_out_srwm(
    const float* __restrict__ gin, float* __restrict__ outp,
    const float* __restrict__ Wy0, const float* __restrict__ Wq0,
    const float* __restrict__ Wk0, const float* __restrict__ wb0,
    const float* __restrict__ lng, const float* __restrict__ lnb,
    const float* __restrict__ outW, const float* __restrict__ outb) {
  const int t = threadIdx.x;
  const int lane = t & 63;
  const int w = t >> 6;
  const int hh = t >> 4, r = t & 15;
  const int b = blockIdx.x;
  __shared__ float ymat[16][256];
  __shared__ float gwm[cNC][256];
  __shared__ float GBp[4][10];
  __shared__ float GBs[10];
  __shared__ __align__(16) float gscr[16][GSTR];
  float* gl = gscr[hh];
  float wy[16], wq[16], wk[16], wbr[16];
#pragma unroll
  for (int j = 0; j < 16; ++j) {
    wy[j]  = Wy0[(hh * 16 + r) * 16 + j];
    wq[j]  = Wq0[(hh * 16 + r) * 16 + j];
    wk[j]  = Wk0[(hh * 16 + r) * 16 + j];
    wbr[j] = wb0[(hh * 4 + (r & 3)) * 16 + j];
  }
  {
    const float gg = lng[t], bbl = lnb[t];
    float pg[cNC], pbv[cNC];
#pragma unroll
    for (int c = 0; c < cNC; ++c) {
      const float wv = outW[(size_t)t * cNC + c];
      const float gwv = gg * wv;
      gwm[c][t] = gwv;
      pg[c] = wave_sum64(gwv);
      pbv[c] = wave_sum64(bbl * wv);
    }
    if (lane == 0) {
#pragma unroll
      for (int c = 0; c < cNC; ++c) { GBp[w][c] = pg[c]; GBp[w][5 + c] = pbv[c]; }
    }
    __syncthreads();
    if (t < 10) GBs[t] = GBp[0][t] + GBp[1][t] + GBp[2][t] + GBp[3][t];
    __syncthreads();
  }
  float xp[16];
#pragma unroll
  for (int s = 0; s < 16; ++s) xp[s] = gin[(size_t)(s * cB + b) * cD + t];
  srwm_prestage(xp, gl, r);
  for (int s = 0; s < cS; ++s)
    ymat[s][t] = srwm_step(wy, wq, wk, wbr, gl, r, s);
  __syncthreads();
  for (int k2 = 0; k2 < 4; ++k2) {
    const int sidx = w * 4 + k2;
    const float4 y4 = ((const float4*)ymat[sidx])[lane];
    const float s1 = wave_sum64(y4.x + y4.y + y4.z + y4.w);
    const float s2 = wave_sum64(y4.x * y4.x + y4.y * y4.y + y4.z * y4.z + y4.w * y4.w);
    float S[cNC];
#pragma unroll
    for (int c = 0; c < cNC; ++c) {
      const float4 g4 = ((const float4*)gwm[c])[lane];
      S[c] = wave_sum64(y4.x * g4.x + y4.y * g4.y + y4.z * g4.z + y4.w * g4.w);
    }
    if (lane == 0) {
      const float m = s1 * (1.f / 256.f);
      const float var = s2 * (1.f / 256.f) - m * m;
      const float rst = rsqrtf(var + LEPS);
#pragma unroll
      for (int c = 0; c < cNC; ++c) {
        outp[(size_t)(sidx * cB + b) * cNC + c] =
            outb[c] + rst * S[c] - rst * m * GBs[c] + GBs[5 + c];
      }
    }
  }
}

extern "C" void kernel_launch(void* const* d_in, const int* in_sizes, int n_in,
                              void* d_out, int out_size, void* d_ws, size_t ws_size,
                              hipStream_t stream) {
  const float* x     = (const float*)d_in[0];
  const int*   fb    = (const int*)d_in[1];
  const float* inW   = (const float*)d_in[2];
  const float* inb   = (const float*)d_in[3];
  const float* tkWy  = (const float*)d_in[4];
  const float* tkWq  = (const float*)d_in[5];
  const float* tkWk  = (const float*)d_in[6];
  const float* tkwb  = (const float*)d_in[7];
  const float* tklng = (const float*)d_in[8];
  const float* tklnb = (const float*)d_in[9];
  const float* tkmg  = (const float*)d_in[10];
  const float* tkmb  = (const float*)d_in[11];
  const float* tkmW1 = (const float*)d_in[12];
  const float* tkmb1 = (const float*)d_in[13];
  const float* tkmW2 = (const float*)d_in[14];
  const float* tkmb2 = (const float*)d_in[15];
  const float* chWy  = (const float*)d_in[16];
  const float* chWq  = (const float*)d_in[17];
  const float* chWk  = (const float*)d_in[18];
  const float* chwb  = (const float*)d_in[19];
  const float* chlng = (const float*)d_in[20];
  const float* chlnb = (const float*)d_in[21];
  const float* chmg  = (const float*)d_in[22];
  const float* chmb  = (const float*)d_in[23];
  const float* chmW1 = (const float*)d_in[24];
  const float* chmb1 = (const float*)d_in[25];
  const float* chmW2 = (const float*)d_in[26];
  const float* chmb2 = (const float*)d_in[27];
  const float* flng  = (const float*)d_in[28];
  const float* flnb  = (const float*)d_in[29];
  const float* oWy   = (const float*)d_in[30];
  const float* oWq   = (const float*)d_in[31];
  const float* oWk   = (const float*)d_in[32];
  const float* owb   = (const float*)d_in[33];
  const float* olng  = (const float*)d_in[34];
  const float* olnb  = (const float*)d_in[35];
  const float* outW  = (const float*)d_in[36];
  const float* outb  = (const float*)d_in[37];

  float* h    = (float*)d_ws;                               // (S,B,P,D) 2 MB
  float* gbuf = h + (size_t)cS * cB * cP * cD;              // (S,B,D)
  float* y2   = gbuf + (size_t)cS * cB * cD;                // (S,B,P,D) 2 MB scratch
  float* outp = (float*)d_out;                              // (S,B,NC)

  k_embed<<<dim3(cS * cB * cP), dim3(256), 0, stream>>>(x, fb, inW, inb, h);
  for (int i = 0; i < 2; ++i) {
    k_tok_srwm<<<dim3(256), dim3(128), 0, stream>>>(
        h, tkWy + i * 256, tkWq + i * 256, tkWk + i * 256, tkwb + i * 64,
        tklng + i * 16, tklnb + i * 16);
    k_tok_mixer<<<dim3(cS * cB), dim3(256), 0, stream>>>(
        h, tkmg + i * 256, tkmb + i * 256, tkmW1 + i * 1024, tkmb1 + i * 64,
        tkmW2 + i * 1024, tkmb2 + i * 16);
    k_ch_scan<<<dim3(cB * cP * 2), dim3(128), 0, stream>>>(
        h, y2, chWy + i * 4096, chWq + i * 4096, chWk + i * 4096, chwb + i * 1024);
    k_ch_ln_mix<<<dim3(cS * cB * cP / 8), dim3(512), 0, stream>>>(
        y2, h, chlng + i * 256, chlnb + i * 256,
        chmg + i * 256, chmb + i * 256, chmW1 + i * 32768, chmb1 + i * 128,
        chmW2 + i * 32768, chmb2 + i * 256);
  }
  k_fln_mean<<<dim3(cS * cB), dim3(256), 0, stream>>>(h, flng, flnb, gbuf);
  k_out_srwm<<<dim3(cB), dim3(256), 0, stream>>>(
      gbuf, outp, oWy, oWq, oWk, owb, olng, olnb, outW, outb);
}